// Round 1
// baseline (24577.560 us; speedup 1.0000x reference)
//
#include <hip/hip_runtime.h>
#include <math.h>

// Problem constants (fixed by the harness).
#define BB 4096
#define TT 2048
#define LL 100

constexpr int NB = 16;        // batch chains per workgroup
constexpr int WG = 512;       // threads per workgroup (8 waves)
constexpr int H1STRIDE = 116; // padded LDS row stride (floats): 116*4=464B, 16B-aligned, banks spread
constexpr int XTILE = 64;     // input timesteps staged per LDS tile

__device__ __forceinline__ float fsig(float x) {
    // 1/(1+e^-x); __expf -> v_exp_f32 path, ~2ulp. Saturates cleanly at +-inf.
    return 1.0f / (1.0f + __expf(-x));
}
__device__ __forceinline__ float ftanh(float x) {
    // tanh via exp(2|x|): overflow-safe (e=inf -> r=1), then restore sign.
    float a = fabsf(x);
    float e = __expf(2.0f * a);
    float r = 1.0f - 2.0f / (e + 1.0f);
    return copysignf(r, x);
}

__global__ __launch_bounds__(WG, 2)
void lstm2_kernel(const float* __restrict__ input,   // [B,T]
                  const float* __restrict__ W_ih1,   // [400,1]
                  const float* __restrict__ W_hh1,   // [400,100]
                  const float* __restrict__ b_ih1,   // [400]
                  const float* __restrict__ b_hh1,   // [400]
                  const float* __restrict__ W_ih2,   // [4,100]
                  const float* __restrict__ W_hh2,   // [4,1]
                  const float* __restrict__ b_ih2,   // [4]
                  const float* __restrict__ b_hh2,   // [4]
                  float* __restrict__ out)           // [B,T]
{
    __shared__ __align__(16) float h1buf[2][NB][H1STRIDE]; // double-buffered h1 state
    __shared__ float xs[NB][XTILE];                        // staged input tile

    const int tid = threadIdx.x;
    const int bg0 = blockIdx.x * NB;

    // Zero h1 buffers (including col padding 100..115 -> must stay 0 forever).
    for (int i = tid; i < 2 * NB * H1STRIDE; i += WG)
        (&h1buf[0][0][0])[i] = 0.0f;

    const bool isL1 = (tid < 4 * LL);   // threads 0..399
    const bool isL2 = (tid >= 448);     // wave 7: 64 lanes = 16 items x 4 gates

    // ---- per-thread persistent state ----
    // wreg is shared storage: layer-1 threads use [0..111] as W_hh1 slices,
    // layer-2 threads use [0..99] as a W_ih2 row (keeps total VGPRs ~160).
    float wreg[112];
    float wx[4], bias[4];
    float c1[NB];

    const int s = tid & 3;    // col slice (28 cols each, zero-padded)
    const int k = tid >> 2;   // hidden unit 0..99

    if (isL1) {
#pragma unroll
        for (int g = 0; g < 4; ++g) {
            const int row = g * LL + k;
#pragma unroll
            for (int j = 0; j < 28; ++j) {
                const int c = 28 * s + j;
                wreg[g * 28 + j] = (c < LL) ? W_hh1[row * LL + c] : 0.0f;
            }
            wx[g] = W_ih1[row];
            bias[g] = b_ih1[row] + b_hh1[row];
        }
#pragma unroll
        for (int b = 0; b < NB; ++b) c1[b] = 0.0f;
    }

    const int m = tid - 448;       // lane within wave 7
    const int b2i = (m >> 2) & 15; // item
    const int gg = m & 3;          // gate (i,f,g,o)
    float wh2 = 0.0f, bias2 = 0.0f, h2 = 0.0f, c2 = 0.0f;
    if (isL2) {
#pragma unroll
        for (int j = 0; j < LL; ++j) wreg[j] = W_ih2[gg * LL + j];
        wh2 = W_hh2[gg];
        bias2 = b_ih2[gg] + b_hh2[gg];
    }

    __syncthreads();

    // t = 0..T-1: layer-1 computes h1_t ; wave 7 (t>=1) computes h2_{t-1} (one step behind).
    // t = T: layer-2 tail only.
    for (int t = 0; t <= TT; ++t) {
        if ((t & (XTILE - 1)) == 0 && t < TT) {
            // stage next 64 timesteps of input for our 16 items (coalesced)
            for (int u = tid; u < NB * XTILE; u += WG) {
                const int b = u >> 6, ti = u & (XTILE - 1);
                xs[b][ti] = input[(size_t)(bg0 + b) * TT + t + ti];
            }
            __syncthreads();
        }
        const int cur = t & 1, prev = cur ^ 1;

        if (t < TT && isL1) {
            const float* hb = &h1buf[prev][0][0];
#pragma unroll 1
            for (int b = 0; b < NB; ++b) {
                const float* hrow = hb + b * H1STRIDE + 28 * s;
                float a0 = 0.f, a1 = 0.f, a2 = 0.f, a3 = 0.f;
#pragma unroll
                for (int jb = 0; jb < 7; ++jb) {
                    const float4 h4 = *(const float4*)(hrow + 4 * jb);
                    a0 = fmaf(wreg[0 * 28 + 4 * jb + 0], h4.x, a0);
                    a1 = fmaf(wreg[1 * 28 + 4 * jb + 0], h4.x, a1);
                    a2 = fmaf(wreg[2 * 28 + 4 * jb + 0], h4.x, a2);
                    a3 = fmaf(wreg[3 * 28 + 4 * jb + 0], h4.x, a3);
                    a0 = fmaf(wreg[0 * 28 + 4 * jb + 1], h4.y, a0);
                    a1 = fmaf(wreg[1 * 28 + 4 * jb + 1], h4.y, a1);
                    a2 = fmaf(wreg[2 * 28 + 4 * jb + 1], h4.y, a2);
                    a3 = fmaf(wreg[3 * 28 + 4 * jb + 1], h4.y, a3);
                    a0 = fmaf(wreg[0 * 28 + 4 * jb + 2], h4.z, a0);
                    a1 = fmaf(wreg[1 * 28 + 4 * jb + 2], h4.z, a1);
                    a2 = fmaf(wreg[2 * 28 + 4 * jb + 2], h4.z, a2);
                    a3 = fmaf(wreg[3 * 28 + 4 * jb + 2], h4.z, a3);
                    a0 = fmaf(wreg[0 * 28 + 4 * jb + 3], h4.w, a0);
                    a1 = fmaf(wreg[1 * 28 + 4 * jb + 3], h4.w, a1);
                    a2 = fmaf(wreg[2 * 28 + 4 * jb + 3], h4.w, a2);
                    a3 = fmaf(wreg[3 * 28 + 4 * jb + 3], h4.w, a3);
                }
                // reduce across the 4 col-slices (lane bits 0..1) -> all 4 lanes get full sums
                a0 += __shfl_xor(a0, 1); a0 += __shfl_xor(a0, 2);
                a1 += __shfl_xor(a1, 1); a1 += __shfl_xor(a1, 2);
                a2 += __shfl_xor(a2, 1); a2 += __shfl_xor(a2, 2);
                a3 += __shfl_xor(a3, 1); a3 += __shfl_xor(a3, 2);

                const float xt = xs[b][t & (XTILE - 1)];
                const float pi = a0 + wx[0] * xt + bias[0];
                const float pf = a1 + wx[1] * xt + bias[1];
                const float pg = a2 + wx[2] * xt + bias[2];
                const float po = a3 + wx[3] * xt + bias[3];

                const float ig = fsig(pi);
                const float fg = fsig(pf);
                const float gv = ftanh(pg);
                const float og = fsig(po);

                const float c = fg * c1[b] + ig * gv;
                c1[b] = c;
                const float h = og * ftanh(c);
                if (s == 0) h1buf[cur][b][k] = h;
            }
        }

        if (t >= 1 && isL2) {
            // layer 2 for step t-1, reading h1_{t-1} (= buffer 'prev')
            const float* hrow = &h1buf[prev][b2i][0];
            float acc = 0.0f;
#pragma unroll
            for (int jb = 0; jb < 25; ++jb) {
                const float4 h4 = *(const float4*)(hrow + 4 * jb);
                acc = fmaf(wreg[4 * jb + 0], h4.x, acc);
                acc = fmaf(wreg[4 * jb + 1], h4.y, acc);
                acc = fmaf(wreg[4 * jb + 2], h4.z, acc);
                acc = fmaf(wreg[4 * jb + 3], h4.w, acc);
            }
            const float pre = acc + wh2 * h2 + bias2;
            const float v = (gg == 2) ? ftanh(pre) : fsig(pre);
            const int base = m & ~3;
            const float vi = __shfl(v, base + 0);
            const float vf = __shfl(v, base + 1);
            const float vg = __shfl(v, base + 2);
            const float vo = __shfl(v, base + 3);
            c2 = vf * c2 + vi * vg;
            h2 = vo * ftanh(c2);
            if (gg == 0) out[(size_t)(bg0 + b2i) * TT + (t - 1)] = h2;
        }

        __syncthreads();
    }
}

extern "C" void kernel_launch(void* const* d_in, const int* in_sizes, int n_in,
                              void* d_out, int out_size, void* d_ws, size_t ws_size,
                              hipStream_t stream) {
    const float* input = (const float*)d_in[0];
    const float* W_ih1 = (const float*)d_in[1];
    const float* W_hh1 = (const float*)d_in[2];
    const float* b_ih1 = (const float*)d_in[3];
    const float* b_hh1 = (const float*)d_in[4];
    const float* W_ih2 = (const float*)d_in[5];
    const float* W_hh2 = (const float*)d_in[6];
    const float* b_ih2 = (const float*)d_in[7];
    const float* b_hh2 = (const float*)d_in[8];
    float* out = (float*)d_out;

    dim3 grid(BB / NB);   // 256 workgroups, 16 chains each
    dim3 block(WG);       // 512 threads = 8 waves
    lstm2_kernel<<<grid, block, 0, stream>>>(input, W_ih1, W_hh1, b_ih1, b_hh1,
                                             W_ih2, W_hh2, b_ih2, b_hh2, out);
}

// Round 2
// 24018.295 us; speedup vs baseline: 1.0233x; 1.0233x over previous
//
#include <hip/hip_runtime.h>
#include <math.h>

// Problem constants (fixed by the harness).
#define BB 4096
#define TT 2048
#define LL 100

constexpr int NB = 16;        // batch chains per workgroup
constexpr int WG = 512;       // threads per workgroup (8 waves)
constexpr int H1STRIDE = 116; // padded LDS row stride (floats): 116*4=464B, 16B-aligned, banks spread
constexpr int XTILE = 64;     // input timesteps staged per LDS tile

__device__ __forceinline__ float fsig(float x) {
    // 1/(1+e^-x); __expf -> v_exp_f32 path, ~2ulp. Saturates cleanly at +-inf.
    return 1.0f / (1.0f + __expf(-x));
}
__device__ __forceinline__ float ftanh(float x) {
    // tanh via exp(2|x|): overflow-safe (e=inf -> r=1), then restore sign.
    float a = fabsf(x);
    float e = __expf(2.0f * a);
    float r = 1.0f - 2.0f / (e + 1.0f);
    return copysignf(r, x);
}

// waves_per_eu(2,2): pin the backend's occupancy target. With only
// __launch_bounds__(512,2) (a MIN), the allocator targeted ~5 waves/EU and
// spilled the 112-float weight array to AGPRs (VGPR_Count=92 < 112 in R1),
// inflating VALU inst ~2.4x. One 8-wave block/CU is all we ever get (grid=256),
// so 2 waves/EU exactly = 256-VGPR budget.
__global__ void __launch_bounds__(WG)
__attribute__((amdgpu_waves_per_eu(2, 2)))
lstm2_kernel(const float* __restrict__ input,   // [B,T]
             const float* __restrict__ W_ih1,   // [400,1]
             const float* __restrict__ W_hh1,   // [400,100]
             const float* __restrict__ b_ih1,   // [400]
             const float* __restrict__ b_hh1,   // [400]
             const float* __restrict__ W_ih2,   // [4,100]
             const float* __restrict__ W_hh2,   // [4,1]
             const float* __restrict__ b_ih2,   // [4]
             const float* __restrict__ b_hh2,   // [4]
             float* __restrict__ out)           // [B,T]
{
    __shared__ __align__(16) float h1buf[2][NB][H1STRIDE]; // double-buffered h1 state
    __shared__ float xs[NB][XTILE];                        // staged input tile

    const int tid = threadIdx.x;
    const int bg0 = blockIdx.x * NB;

    // Zero h1 buffers (including col padding 100..115 -> must stay 0 forever).
    for (int i = tid; i < 2 * NB * H1STRIDE; i += WG)
        (&h1buf[0][0][0])[i] = 0.0f;

    const bool isL1 = (tid < 4 * LL);   // threads 0..399
    const bool isL2 = (tid >= 448);     // wave 7: 64 lanes = 16 items x 4 gates

    // ---- per-thread persistent state ----
    // wreg is shared storage: layer-1 threads use [0..111] as W_hh1 slices,
    // layer-2 threads use [0..99] as a W_ih2 row (keeps total VGPRs ~160).
    float wreg[112];
    float wx[4], bias[4];
    float c1[NB];

    const int s = tid & 3;    // col slice (28 cols each, zero-padded)
    const int k = tid >> 2;   // hidden unit 0..99

    if (isL1) {
#pragma unroll
        for (int g = 0; g < 4; ++g) {
            const int row = g * LL + k;
#pragma unroll
            for (int j = 0; j < 28; ++j) {
                const int c = 28 * s + j;
                wreg[g * 28 + j] = (c < LL) ? W_hh1[row * LL + c] : 0.0f;
            }
            wx[g] = W_ih1[row];
            bias[g] = b_ih1[row] + b_hh1[row];
        }
#pragma unroll
        for (int b = 0; b < NB; ++b) c1[b] = 0.0f;
    }

    const int m = tid - 448;       // lane within wave 7
    const int b2i = (m >> 2) & 15; // item
    const int gg = m & 3;          // gate (i,f,g,o)
    float wh2 = 0.0f, bias2 = 0.0f, h2 = 0.0f, c2 = 0.0f;
    if (isL2) {
#pragma unroll
        for (int j = 0; j < LL; ++j) wreg[j] = W_ih2[gg * LL + j];
        wh2 = W_hh2[gg];
        bias2 = b_ih2[gg] + b_hh2[gg];
    }

    __syncthreads();

    // t = 0..T-1: layer-1 computes h1_t ; wave 7 (t>=1) computes h2_{t-1} (one step behind).
    // t = T: layer-2 tail only.
    for (int t = 0; t <= TT; ++t) {
        if ((t & (XTILE - 1)) == 0 && t < TT) {
            // stage next 64 timesteps of input for our 16 items (coalesced)
            for (int u = tid; u < NB * XTILE; u += WG) {
                const int b = u >> 6, ti = u & (XTILE - 1);
                xs[b][ti] = input[(size_t)(bg0 + b) * TT + t + ti];
            }
            __syncthreads();
        }
        const int cur = t & 1, prev = cur ^ 1;

        if (t < TT && isL1) {
            const float* hb = &h1buf[prev][0][0];
#pragma unroll 1
            for (int b = 0; b < NB; ++b) {
                const float* hrow = hb + b * H1STRIDE + 28 * s;
                float a0 = 0.f, a1 = 0.f, a2 = 0.f, a3 = 0.f;
#pragma unroll
                for (int jb = 0; jb < 7; ++jb) {
                    const float4 h4 = *(const float4*)(hrow + 4 * jb);
                    a0 = fmaf(wreg[0 * 28 + 4 * jb + 0], h4.x, a0);
                    a1 = fmaf(wreg[1 * 28 + 4 * jb + 0], h4.x, a1);
                    a2 = fmaf(wreg[2 * 28 + 4 * jb + 0], h4.x, a2);
                    a3 = fmaf(wreg[3 * 28 + 4 * jb + 0], h4.x, a3);
                    a0 = fmaf(wreg[0 * 28 + 4 * jb + 1], h4.y, a0);
                    a1 = fmaf(wreg[1 * 28 + 4 * jb + 1], h4.y, a1);
                    a2 = fmaf(wreg[2 * 28 + 4 * jb + 1], h4.y, a2);
                    a3 = fmaf(wreg[3 * 28 + 4 * jb + 1], h4.y, a3);
                    a0 = fmaf(wreg[0 * 28 + 4 * jb + 2], h4.z, a0);
                    a1 = fmaf(wreg[1 * 28 + 4 * jb + 2], h4.z, a1);
                    a2 = fmaf(wreg[2 * 28 + 4 * jb + 2], h4.z, a2);
                    a3 = fmaf(wreg[3 * 28 + 4 * jb + 2], h4.z, a3);
                    a0 = fmaf(wreg[0 * 28 + 4 * jb + 3], h4.w, a0);
                    a1 = fmaf(wreg[1 * 28 + 4 * jb + 3], h4.w, a1);
                    a2 = fmaf(wreg[2 * 28 + 4 * jb + 3], h4.w, a2);
                    a3 = fmaf(wreg[3 * 28 + 4 * jb + 3], h4.w, a3);
                }
                // reduce across the 4 col-slices (lane bits 0..1) -> all 4 lanes get full sums
                a0 += __shfl_xor(a0, 1); a0 += __shfl_xor(a0, 2);
                a1 += __shfl_xor(a1, 1); a1 += __shfl_xor(a1, 2);
                a2 += __shfl_xor(a2, 1); a2 += __shfl_xor(a2, 2);
                a3 += __shfl_xor(a3, 1); a3 += __shfl_xor(a3, 2);

                const float xt = xs[b][t & (XTILE - 1)];
                const float pi = a0 + wx[0] * xt + bias[0];
                const float pf = a1 + wx[1] * xt + bias[1];
                const float pg = a2 + wx[2] * xt + bias[2];
                const float po = a3 + wx[3] * xt + bias[3];

                const float ig = fsig(pi);
                const float fg = fsig(pf);
                const float gv = ftanh(pg);
                const float og = fsig(po);

                const float c = fg * c1[b] + ig * gv;
                c1[b] = c;
                const float h = og * ftanh(c);
                if (s == 0) h1buf[cur][b][k] = h;
            }
        }

        if (t >= 1 && isL2) {
            // layer 2 for step t-1, reading h1_{t-1} (= buffer 'prev')
            const float* hrow = &h1buf[prev][b2i][0];
            float acc = 0.0f;
#pragma unroll
            for (int jb = 0; jb < 25; ++jb) {
                const float4 h4 = *(const float4*)(hrow + 4 * jb);
                acc = fmaf(wreg[4 * jb + 0], h4.x, acc);
                acc = fmaf(wreg[4 * jb + 1], h4.y, acc);
                acc = fmaf(wreg[4 * jb + 2], h4.z, acc);
                acc = fmaf(wreg[4 * jb + 3], h4.w, acc);
            }
            const float pre = acc + wh2 * h2 + bias2;
            const float v = (gg == 2) ? ftanh(pre) : fsig(pre);
            const int base = m & ~3;
            const float vi = __shfl(v, base + 0);
            const float vf = __shfl(v, base + 1);
            const float vg = __shfl(v, base + 2);
            const float vo = __shfl(v, base + 3);
            c2 = vf * c2 + vi * vg;
            h2 = vo * ftanh(c2);
            if (gg == 0) out[(size_t)(bg0 + b2i) * TT + (t - 1)] = h2;
        }

        __syncthreads();
    }
}

extern "C" void kernel_launch(void* const* d_in, const int* in_sizes, int n_in,
                              void* d_out, int out_size, void* d_ws, size_t ws_size,
                              hipStream_t stream) {
    const float* input = (const float*)d_in[0];
    const float* W_ih1 = (const float*)d_in[1];
    const float* W_hh1 = (const float*)d_in[2];
    const float* b_ih1 = (const float*)d_in[3];
    const float* b_hh1 = (const float*)d_in[4];
    const float* W_ih2 = (const float*)d_in[5];
    const float* W_hh2 = (const float*)d_in[6];
    const float* b_ih2 = (const float*)d_in[7];
    const float* b_hh2 = (const float*)d_in[8];
    float* out = (float*)d_out;

    dim3 grid(BB / NB);   // 256 workgroups, 16 chains each
    dim3 block(WG);       // 512 threads = 8 waves
    lstm2_kernel<<<grid, block, 0, stream>>>(input, W_ih1, W_hh1, b_ih1, b_hh1,
                                             W_ih2, W_hh2, b_ih2, b_hh2, out);
}